// Round 8
// baseline (326.707 us; speedup 1.0000x reference)
//
#include <hip/hip_runtime.h>
#include <hip/hip_fp16.h>

// TwoDimensionalSSM via direct 2D recurrence. Round 14: single shared partial
// accumulator via ds_pk_add_f16.
// R13 post-mortem: pass-split won (122->114.5us, occupancy 36->55%, waves
// ~11.5->~17.6/CU). Residual: busy ~99us, idle ~15us, LDS 48KB -> 3 blocks/CU.
// This round: replace the two 16KB partial buffers with ONE 16KB __half2
// accumulator that both passes unsafeAtomicAdd (ds_pk_add_f16, gfx940+) into:
//   - LDS 48->32KB -> 4 blocks/CU = 32 waves/CU theoretical (100% of slots)
//   - combine loop halves (1 ds_read per pixel-pair, no add)
//   - per-iter ds_write_b16 -> shift + pk-atomic (+1 VALU, partner half +0.0)
// Atomic conflicts: within a wave, pass A (row s) and pass B (row s^31) have
// opposite rr&1 -> disjoint bank halves; 2 lanes per half2 address = free.
// If occupancy does NOT move, the LDS-caps-occupancy theory is falsified.
// Inner math identical to R13 (pk_fma_f16 / pk_fmac_f16_dpp / fdot2).

#define NPB 8            // images per block
#define THREADS 512      // 8 waves; half-slot (t>>5) = (img<<1)|flip
#define M_TOT 16384      // B*E
#define SCALE 0.70710678118654752f  // sqrt(1/N), N=2

typedef __attribute__((ext_vector_type(2))) _Float16 v2h;

__device__ __forceinline__ unsigned h2u(v2h v) { return __builtin_bit_cast(unsigned, v); }
__device__ __forceinline__ v2h u2h(unsigned v) { return __builtin_bit_cast(v2h, v); }
__device__ __forceinline__ v2h hfma2v(v2h a, v2h b, v2h c) {
    return __builtin_elementwise_fma(a, b, c);   // -> v_pk_fma_f16
}
__device__ __forceinline__ v2h cvt2(float x, float y) {
    return (v2h){(_Float16)x, (_Float16)y};
}

template<int CTRL>
__device__ __forceinline__ v2h dpph(v2h v) {   // packed mov_dpp (whole 32b reg)
    return u2h((unsigned)__builtin_amdgcn_update_dpp(
        0, (int)h2u(v), CTRL, 0xF, 0xF, true));
}
// full 32-lane reversal within each 32-half: bit-mode xor_mask=0x1F
__device__ __forceinline__ float swzrev(float v) {
    return __int_as_float(__builtin_amdgcn_ds_swizzle(__float_as_int(v), 0x7C1F));
}
__device__ __forceinline__ float sigm(float v) { return 1.0f / (1.0f + __expf(-v)); }

struct DirPH {
    v2h a1, p2, p4, p8, w;            // scan coefficients (n0,n1 packed)
    v2h a2z, ab, a3, a4, b1, b2, a3b1, c1, c2;
    float k00;
};

// Unified forward-scan init (rev dirs run in reversed lane space; edge kill at
// j==0 covers fwd col-0 leak, rev col-31 leak, and the wave_shr cross-half leak)
__device__ __forceinline__ void dir_init_h(DirPH& P, int h, int j,
    const float* __restrict__ A1p, const float* __restrict__ A2p,
    const float* __restrict__ A3p, const float* __restrict__ A4p,
    const float* __restrict__ B1p, const float* __restrict__ B2p,
    const float* __restrict__ C1p, const float* __restrict__ C2p)
{
    float2 a1r = *(const float2*)(A1p + 2 * h);
    float2 a2r = *(const float2*)(A2p + 2 * h);
    float2 a3r = *(const float2*)(A3p + 2 * h);
    float2 a4r = *(const float2*)(A4p + 2 * h);
    float2 b1r = *(const float2*)(B1p + 2 * h);
    float2 b2r = *(const float2*)(B2p + 2 * h);
    float2 c1r = *(const float2*)(C1p + 2 * h);
    float2 c2r = *(const float2*)(C2p + 2 * h);
    float a1v0 = sigm(a1r.x), a1v1 = sigm(a1r.y);
    float p2v0 = a1v0 * a1v0, p2v1 = a1v1 * a1v1;
    float p4v0 = p2v0 * p2v0, p4v1 = p2v1 * p2v1;
    float p8v0 = p4v0 * p4v0, p8v1 = p4v1 * p4v1;
    float a3v0 = sigm(a3r.x), a3v1 = sigm(a3r.y);
    float a4v0 = sigm(a4r.x), a4v1 = sigm(a4r.y);
    float b1v0 = sigm(b1r.x), b1v1 = sigm(b1r.y);
    float b2v0 = sigm(b2r.x), b2v1 = sigm(b2r.y);
    float c1v0 = SCALE * c1r.x, c1v1 = SCALE * c1r.y;
    float c2v0 = SCALE * c2r.x, c2v1 = SCALE * c2r.y;
    P.a1 = cvt2(a1v0, a1v1); P.p2 = cvt2(p2v0, p2v1);
    P.p4 = cvt2(p4v0, p4v1); P.p8 = cvt2(p8v0, p8v1);
    P.a3 = cvt2(a3v0, a3v1); P.a4 = cvt2(a4v0, a4v1);
    P.b1 = cvt2(b1v0, b1v1); P.b2 = cvt2(b2v0, b2v1);
    P.a3b1 = cvt2(a3v0 * b1v0, a3v1 * b1v1);
    P.c1 = cvt2(c1v0, c1v1); P.c2 = cvt2(c2v0, c2v1);
    P.k00 = c1v0 * b1v0 + c1v1 * b1v1 + c2v0 * b2v0 + c2v1 * b2v1;
    const bool edge = (j == 0);
    float z0 = edge ? 0.f : sigm(a2r.x);
    float z1 = edge ? 0.f : sigm(a2r.y);
    P.a2z = cvt2(z0, z1);
    P.ab  = cvt2(z0 * b2v0, z1 * b2v1);
    float e = (float)((j & 15) + 1);
    P.w = cvt2(__powf(a1v0, e), __powf(a1v1, e));
}

// recurrence front-end (forward form, all dirs): nxv, ncx and scan inputs d, e
__device__ __forceinline__ void dir_pre_h(const DirPH& P, v2h u2, v2h up2,
    v2h xh, v2h xv, v2h cx, v2h& nxv, v2h& ncx, v2h& d, v2h& e)
{
    v2h b2u = P.b2 * u2;
    nxv = hfma2v(P.a3, xh, hfma2v(P.a4, xv, b2u));
    ncx = hfma2v(P.a3b1, up2, hfma2v(P.a4, cx, b2u));
    v2h xl = dpph<0x138>(nxv);    // wave_shr:1 (neighbor lane j-1), packed
    v2h ul = dpph<0x138>(u2);
    v2h b1u = P.b1 * u2;
    d = hfma2v(P.a2z, xl, b1u);
    e = hfma2v(P.ab, ul, b1u);
}

// dot (f32 accumulate via v_dot2_f32_f16) + state update
__device__ __forceinline__ float dir_post_h(const DirPH& P, v2h nh, v2h rh,
    v2h nxv, v2h ncx, v2h& xh, v2h& xv, v2h& cx, float base)
{
    v2h s1 = nh + rh;
    v2h s2 = nxv + ncx;
    float y = __builtin_amdgcn_fdot2(P.c1, s1,
              __builtin_amdgcn_fdot2(P.c2, s2, base, false), false);
    xh = nh; xv = nxv; cx = ncx;
    return y;
}

// 4 packed forward scan chains, 5 stages, ONE v_pk_fmac_f16_dpp per stage per
// chain. 4-wide interleave covers DPP wait states; s_nop 1 guards entry.
__device__ __forceinline__ void scan4h(
    unsigned& f0, unsigned& f1, unsigned& r0, unsigned& r1,
    const DirPH& PF, const DirPH& PR)
{
    asm("s_nop 1\n\t"
        // ---- stage 1: row_shr:1 ----
        "v_pk_fmac_f16_dpp %0, %0, %4  row_shr:1 row_mask:0xf bank_mask:0xf bound_ctrl:0\n\t"
        "v_pk_fmac_f16_dpp %1, %1, %4  row_shr:1 row_mask:0xf bank_mask:0xf bound_ctrl:0\n\t"
        "v_pk_fmac_f16_dpp %2, %2, %9  row_shr:1 row_mask:0xf bank_mask:0xf bound_ctrl:0\n\t"
        "v_pk_fmac_f16_dpp %3, %3, %9  row_shr:1 row_mask:0xf bank_mask:0xf bound_ctrl:0\n\t"
        // ---- stage 2: row_shr:2 ----
        "v_pk_fmac_f16_dpp %0, %0, %5  row_shr:2 row_mask:0xf bank_mask:0xf bound_ctrl:0\n\t"
        "v_pk_fmac_f16_dpp %1, %1, %5  row_shr:2 row_mask:0xf bank_mask:0xf bound_ctrl:0\n\t"
        "v_pk_fmac_f16_dpp %2, %2, %10 row_shr:2 row_mask:0xf bank_mask:0xf bound_ctrl:0\n\t"
        "v_pk_fmac_f16_dpp %3, %3, %10 row_shr:2 row_mask:0xf bank_mask:0xf bound_ctrl:0\n\t"
        // ---- stage 3: row_shr:4 ----
        "v_pk_fmac_f16_dpp %0, %0, %6  row_shr:4 row_mask:0xf bank_mask:0xf bound_ctrl:0\n\t"
        "v_pk_fmac_f16_dpp %1, %1, %6  row_shr:4 row_mask:0xf bank_mask:0xf bound_ctrl:0\n\t"
        "v_pk_fmac_f16_dpp %2, %2, %11 row_shr:4 row_mask:0xf bank_mask:0xf bound_ctrl:0\n\t"
        "v_pk_fmac_f16_dpp %3, %3, %11 row_shr:4 row_mask:0xf bank_mask:0xf bound_ctrl:0\n\t"
        // ---- stage 4: row_shr:8 ----
        "v_pk_fmac_f16_dpp %0, %0, %7  row_shr:8 row_mask:0xf bank_mask:0xf bound_ctrl:0\n\t"
        "v_pk_fmac_f16_dpp %1, %1, %7  row_shr:8 row_mask:0xf bank_mask:0xf bound_ctrl:0\n\t"
        "v_pk_fmac_f16_dpp %2, %2, %12 row_shr:8 row_mask:0xf bank_mask:0xf bound_ctrl:0\n\t"
        "v_pk_fmac_f16_dpp %3, %3, %12 row_shr:8 row_mask:0xf bank_mask:0xf bound_ctrl:0\n\t"
        // ---- stage 5: rows 1,3 += w * lane15-of-prev-row ----
        "v_pk_fmac_f16_dpp %0, %0, %8  row_bcast:15 row_mask:0xa bank_mask:0xf bound_ctrl:0\n\t"
        "v_pk_fmac_f16_dpp %1, %1, %8  row_bcast:15 row_mask:0xa bank_mask:0xf bound_ctrl:0\n\t"
        "v_pk_fmac_f16_dpp %2, %2, %13 row_bcast:15 row_mask:0xa bank_mask:0xf bound_ctrl:0\n\t"
        "v_pk_fmac_f16_dpp %3, %3, %13 row_bcast:15 row_mask:0xa bank_mask:0xf bound_ctrl:0"
        : "+v"(f0), "+v"(f1), "+v"(r0), "+v"(r1)
        : "v"(h2u(PF.a1)), "v"(h2u(PF.p2)), "v"(h2u(PF.p4)),
          "v"(h2u(PF.p8)), "v"(h2u(PF.w)),
          "v"(h2u(PR.a1)), "v"(h2u(PR.p2)), "v"(h2u(PR.p4)),
          "v"(h2u(PR.p8)), "v"(h2u(PR.w)));
}

__global__ __launch_bounds__(THREADS) void ssm2d_kernel(
    const float* __restrict__ x,
    const float* __restrict__ A1p, const float* __restrict__ A2p,
    const float* __restrict__ A3p, const float* __restrict__ A4p,
    const float* __restrict__ B1p, const float* __restrict__ B2p,
    const float* __restrict__ C1p, const float* __restrict__ C2p,
    const float* __restrict__ omega,
    float* __restrict__ out)
{
    __shared__ _Float16 u_lds[NPB * 1024];   // 16 KB fp16 input, XOR-swizzled
    __shared__ __half2  p_lds2[NPB * 512];   // 16 KB shared partial accumulator
    const int t = threadIdx.x;
    // XCD-aware remap (proven form)
    const int bid = blockIdx.x;
    const int m0  = ((bid & 7) * 256 + (bid >> 3)) * NPB;

    // ---- stage x into LDS (f32 -> fp16); XOR swizzle kills conflicts ----
    const int simg = t & 7;
    #pragma unroll 4
    for (int it = 0; it < 16; ++it) {
        int pix = it * 64 + (t >> 3);
        u_lds[simg * 1024 + (pix ^ (simg << 2))] =
            (_Float16)x[(size_t)pix * M_TOT + (m0 + simg)];
    }
    // ---- zero the shared partial accumulator (same barrier covers both) ----
    {
        uint4* pz = (uint4*)p_lds2;          // 1024 uint4 = 16 KB
        const uint4 z4 = {0u, 0u, 0u, 0u};
        pz[t] = z4;
        pz[t + 512] = z4;
    }
    __syncthreads();

    const int j    = t & 31;
    const int slot = t >> 5;              // 0..15
    const int img  = slot >> 1;           // 0..7
    const int flip = slot & 1;            // 0 = pass A (rows asc), 1 = pass B
    const int m    = m0 + img;
    const int hb   = m & 63;
    const int colx = j ^ (img << 2);      // per-lane swizzled column
    const int colr = 31 ^ colx;           // reversed column's swizzled index
    const int fmask = flip ? 31 : 0;      // 31-s == s^31 for 5-bit s
    const _Float16* uim = u_lds + img * 1024;
    __half2*        pim2 = p_lds2 + img * 512;
    const int xorv  = img << 1;           // bank swizzle for partial buffer
    const int cpj   = j >> 1;             // half2 column-pair (lane j = col j)
    const int shamt = (j & 1) << 4;       // which half of the pair this lane is
    const float om = omega[m & 1023];

    // dirs: flip=0 -> d0 (h=hb) + d2 (h=128+hb); flip=1 -> d1 (64+hb) + d3 (192+hb)
    DirPH PF, PR;
    dir_init_h(PF, hb + (flip << 6),       j, A1p, A2p, A3p, A4p, B1p, B2p, C1p, C2p);
    dir_init_h(PR, 128 + hb + (flip << 6), j, A1p, A2p, A3p, A4p, B1p, B2p, C1p, C2p);
    // per-lane epilogue constant: pass A folds om - k00F, pass B folds -k00F
    const float cF = (flip ? 0.f : om) - PF.k00;

    v2h xhF = {0,0}, xvF = {0,0}, cxF = {0,0};
    v2h xhR = {0,0}, xvR = {0,0}, cxR = {0,0};
    v2h up2 = {0,0}, upr2 = {0,0};
    #pragma unroll 4
    for (int s = 0; s < 32; ++s) {
        const int rr = s ^ fmask;         // logical row this slot processes
        _Float16 uh  = uim[rr * 32 + colx];
        _Float16 urh = uim[rr * 32 + colr];
        float uf = (float)uh, urf = (float)urh;
        v2h u2  = (v2h){uh, uh};
        v2h ur2 = (v2h){urh, urh};
        v2h nxvF, ncxF, dF, eF, nxvR, ncxR, dR, eR;
        dir_pre_h(PF, u2,  up2,  xhF, xvF, cxF, nxvF, ncxF, dF, eF);
        dir_pre_h(PR, ur2, upr2, xhR, xvR, cxR, nxvR, ncxR, dR, eR);
        unsigned f0 = h2u(dF), f1 = h2u(eF), r0 = h2u(dR), r1 = h2u(eR);
        scan4h(f0, f1, r0, r1, PF, PR);
        float yF = dir_post_h(PF, u2h(f0), u2h(f1), nxvF, ncxF,
                              xhF, xvF, cxF, 0.f);
        float yR = dir_post_h(PR, u2h(r0), u2h(r1), nxvR, ncxR,
                              xhR, xvR, cxR, -PR.k00 * urf);
        float yRf = swzrev(yR);           // lane reversal (off cross-row chain)
        // pack this lane's f16 partial into its half of the pair; the other
        // half carries +0.0 (exact no-op under ds_pk_add_f16)
        _Float16 yh = (_Float16)fmaf(uf, cF, yF + yRf);
        unsigned du = ((unsigned)__builtin_bit_cast(unsigned short, yh)) << shamt;
        int a2i = ((rr << 4) + cpj) ^ xorv;
        unsafeAtomicAdd(pim2 + a2i, __builtin_bit_cast(__half2, du));
        up2 = u2; upr2 = ur2;
    }
    __syncthreads();

    // ---- fused SiLU + coalesced store-out (f32), one read per pixel pair ----
    const int tp = t >> 3;                // 0..63
    #pragma unroll 4
    for (int i = 0; i < 8; ++i) {
        int pixp = i * 64 + tp;           // pixel-pair index 0..511
        __half2 v = p_lds2[simg * 512 + (pixp ^ (simg << 1))];
        float z0 = __low2float(v), z1 = __high2float(v);
        float s0 = z0 / (1.0f + __expf(-z0));
        float s1 = z1 / (1.0f + __expf(-z1));
        size_t base = (size_t)(pixp * 2) * M_TOT + (m0 + simg);
        out[base] = s0;
        out[base + M_TOT] = s1;
    }
}

extern "C" void kernel_launch(void* const* d_in, const int* in_sizes, int n_in,
                              void* d_out, int out_size, void* d_ws, size_t ws_size,
                              hipStream_t stream) {
    const float* x  = (const float*)d_in[0];
    const float* A1 = (const float*)d_in[1];
    const float* A2 = (const float*)d_in[2];
    const float* A3 = (const float*)d_in[3];
    const float* A4 = (const float*)d_in[4];
    const float* B1 = (const float*)d_in[5];
    const float* B2 = (const float*)d_in[6];
    const float* C1 = (const float*)d_in[7];
    const float* C2 = (const float*)d_in[8];
    const float* om = (const float*)d_in[9];
    float* out = (float*)d_out;
    hipLaunchKernelGGL(ssm2d_kernel, dim3(M_TOT / NPB), dim3(THREADS), 0, stream,
                       x, A1, A2, A3, A4, B1, B2, C1, C2, om, out);
}